// Round 4
// baseline (100.267 us; speedup 1.0000x reference)
//
#include <hip/hip_runtime.h>
#include <hip/hip_bf16.h>
#include <cstdint>
#include <cstddef>

// Problem constants (B=8, T=64, F=16, E=256, H=8)
constexpr int E = 256;
constexpr int H = 8;
constexpr int D = 32;        // head dim
constexpr int N = 1024;      // T*F positions per (b,h)
constexpr int R = 8192;      // B*N rows
constexpr int BH = 64;       // B*H
constexpr float SCALE = 0.17677669529663687f;   // 1/sqrt(32)
constexpr float LOG2E = 1.4426950408889634f;
constexpr float QSCALE = SCALE * LOG2E;          // folded into bf16 Q

typedef __attribute__((ext_vector_type(8))) short short8;
typedef __attribute__((ext_vector_type(4))) float f32x4;

static __device__ __forceinline__ short bf16bits(float x) {
    __hip_bfloat16 h = __float2bfloat16(x);
    return *reinterpret_cast<short*>(&h);
}
static __device__ __forceinline__ float bf16tof(short s) {
    unsigned int u = ((unsigned int)(unsigned short)s) << 16;
    return *reinterpret_cast<float*>(&u);
}

// ---------------- Kernel B: transpose weights fp32 -> bf16 ---------------------
// Wt4[w][n][k] = W_w[k][n],  w in {q,k,v,o}
__global__ __launch_bounds__(256) void convw_kernel(
    const float* __restrict__ Wq, const float* __restrict__ Wk,
    const float* __restrict__ Wv, const float* __restrict__ Wo,
    short* __restrict__ Wt4)
{
    const int w = blockIdx.y;
    const float* src = (w == 0) ? Wq : (w == 1) ? Wk : (w == 2) ? Wv : Wo;
    short* dst = Wt4 + (size_t)w * E * E;
    const int tr = blockIdx.x >> 2, tc = blockIdx.x & 3;   // 64x64 tiles
    __shared__ float tile[64][65];
    const int tid = threadIdx.x;
    #pragma unroll
    for (int it = 0; it < 16; ++it) {
        int idx = tid + it * 256;
        int r = idx >> 6, c = idx & 63;
        tile[r][c] = src[(size_t)(tr * 64 + r) * E + tc * 64 + c];
    }
    __syncthreads();
    #pragma unroll
    for (int it = 0; it < 16; ++it) {
        int idx = tid + it * 256;
        int r = idx >> 6, c = idx & 63;
        dst[(size_t)(tc * 64 + r) * E + tr * 64 + c] = bf16bits(tile[c][r]);
    }
}

// ---------------- Kernel C: fused QKV projections via MFMA ---------------------
// Reads fp32 X directly, converts A-frags to bf16 in-register.
// Q -> bf16 head-split *QSCALE; K -> bf16 head-split; V -> bf16 row-major.
__global__ __launch_bounds__(256) void proj_mfma(
    const float* __restrict__ q_in, const float* __restrict__ k_in, const float* __restrict__ v_in,
    const short* __restrict__ Wt4,
    const float* __restrict__ bq, const float* __restrict__ bk, const float* __restrict__ bv,
    __hip_bfloat16* __restrict__ Qb16, __hip_bfloat16* __restrict__ Kb16,
    short* __restrict__ Vb16)
{
    const int which = blockIdx.z;
    const float* X  = (which == 0) ? q_in : (which == 1) ? k_in : v_in;
    const short* Wt = Wt4 + (size_t)which * E * E;
    const float* bias = (which == 0) ? bq : (which == 1) ? bk : bv;

    const int wave = threadIdx.x >> 6, lane = threadIdx.x & 63;
    const int l15 = lane & 15, lhi = lane >> 4;
    const int m0 = blockIdx.x * 64 + wave * 16;
    const int n0 = blockIdx.y * 64;

    const float* xrow = X + (size_t)(m0 + l15) * E + lhi * 8;

    f32x4 acc[4] = {};
    for (int k0 = 0; k0 < E; k0 += 32) {
        float4 a0 = *(const float4*)(xrow + k0);
        float4 a1 = *(const float4*)(xrow + k0 + 4);
        short at[8];
        at[0] = bf16bits(a0.x); at[1] = bf16bits(a0.y);
        at[2] = bf16bits(a0.z); at[3] = bf16bits(a0.w);
        at[4] = bf16bits(a1.x); at[5] = bf16bits(a1.y);
        at[6] = bf16bits(a1.z); at[7] = bf16bits(a1.w);
        short8 af = *(short8*)at;
        #pragma unroll
        for (int nt = 0; nt < 4; ++nt) {
            short8 bf = *(const short8*)(Wt + (size_t)(n0 + nt * 16 + l15) * E + k0 + lhi * 8);
            acc[nt] = __builtin_amdgcn_mfma_f32_16x16x32_bf16(af, bf, acc[nt], 0, 0, 0);
        }
    }
    // D layout: row m = m0 + lhi*4 + j (A rows), col n = n0 + nt*16 + l15 (B rows)
    #pragma unroll
    for (int nt = 0; nt < 4; ++nt) {
        #pragma unroll
        for (int j = 0; j < 4; ++j) {
            int m = m0 + lhi * 4 + j;
            int n = n0 + nt * 16 + l15;
            float v = acc[nt][j] + bias[n];
            if (which == 2) {
                Vb16[(size_t)m * E + n] = bf16bits(v);
            } else {
                int b = m >> 10, nl = m & (N - 1);
                int h = n >> 5, dd = n & 31;
                size_t idx = ((size_t)((b * H + h) * N + nl)) * D + dd;
                if (which == 0) Qb16[idx] = __float2bfloat16(v * QSCALE);
                else            Kb16[idx] = __float2bfloat16(v);
            }
        }
    }
}

// ---------------- Kernel D: scores (swapped-operand MFMA softmax) --------------
// Per block: one (b,h), 64 query columns (mc of 16). 4 waves; wave owns 16
// n-tiles (256 rows) and all 4 m-tiles. acc = mfma(qf, kf): lane holds rows m
// (lane-local), col n = l15.
// Pass 1: Z_m partials -> butterfly over l15 once, block-reduce over 4 waves.
// Pass 2: s_n = sum_m exp2(acc)*cinv_m -> in-lane fma + 2 shuffles per n-tile.
__global__ __launch_bounds__(256) void scores_kernel(
    const __hip_bfloat16* __restrict__ Qb16, const __hip_bfloat16* __restrict__ Kb16,
    float* __restrict__ spart)
{
    const int bh = blockIdx.x;   // 0..63
    const int mc = blockIdx.y;   // 0..15
    const int tid  = threadIdx.x;
    const int wave = tid >> 6;   // 0..3
    const int lane = tid & 63;
    const int l15  = lane & 15;
    const int lhi  = lane >> 4;  // 0..3

    const short* Qb = (const short*)Qb16 + (size_t)bh * (N * D);
    const short* Kb = (const short*)Kb16 + (size_t)bh * (N * D);

    __shared__ float zred[4][64];
    __shared__ float cinvS[64];

    // Wave's 4 Q fragments (A operand): rows m = mc*64 + t*16 + l15
    short8 qf[4];
    #pragma unroll
    for (int t = 0; t < 4; ++t) {
        int m = mc * 64 + t * 16 + l15;
        qf[t] = *(const short8*)(Qb + (size_t)m * D + lhi * 8);
    }

    // ---- Pass 1: Z partials over this wave's 256 n rows ----
    float z[4][4];
    #pragma unroll
    for (int t = 0; t < 4; ++t)
        #pragma unroll
        for (int j = 0; j < 4; ++j) z[t][j] = 0.f;

    #pragma unroll 2
    for (int ntl = 0; ntl < 16; ++ntl) {
        int nt = wave * 16 + ntl;
        short8 kf = *(const short8*)(Kb + (size_t)(nt * 16 + l15) * D + lhi * 8);
        #pragma unroll
        for (int t = 0; t < 4; ++t) {
            f32x4 acc = {0.f, 0.f, 0.f, 0.f};
            acc = __builtin_amdgcn_mfma_f32_16x16x32_bf16(qf[t], kf, acc, 0, 0, 0);
            #pragma unroll
            for (int j = 0; j < 4; ++j) z[t][j] += exp2f(acc[j]);
        }
    }
    // butterfly over l15 (sums the 16 n's per tile)
    #pragma unroll
    for (int t = 0; t < 4; ++t)
        #pragma unroll
        for (int j = 0; j < 4; ++j) {
            float v = z[t][j];
            v += __shfl_xor(v, 1); v += __shfl_xor(v, 2);
            v += __shfl_xor(v, 4); v += __shfl_xor(v, 8);
            z[t][j] = v;
        }
    // z[t][j] = partial Z for column m_local = t*16 + lhi*4 + j (wave's n range)
    #pragma unroll
    for (int t = 0; t < 4; ++t) {
        if (l15 == t) {
            #pragma unroll
            for (int j = 0; j < 4; ++j)
                zred[wave][t * 16 + lhi * 4 + j] = z[t][j];
        }
    }
    __syncthreads();
    if (tid < 64) {
        float zs = zred[0][tid] + zred[1][tid] + zred[2][tid] + zred[3][tid];
        cinvS[tid] = 1.0f / zs;
    }
    __syncthreads();

    float ci[4][4];
    #pragma unroll
    for (int t = 0; t < 4; ++t)
        #pragma unroll
        for (int j = 0; j < 4; ++j) ci[t][j] = cinvS[t * 16 + lhi * 4 + j];

    // ---- Pass 2: recompute, in-lane weighted sum over m, write s partials ----
    float* sp = spart + (size_t)(bh * 16 + mc) * N;
    #pragma unroll 2
    for (int ntl = 0; ntl < 16; ++ntl) {
        int nt = wave * 16 + ntl;
        short8 kf = *(const short8*)(Kb + (size_t)(nt * 16 + l15) * D + lhi * 8);
        float rp = 0.f;
        #pragma unroll
        for (int t = 0; t < 4; ++t) {
            f32x4 acc = {0.f, 0.f, 0.f, 0.f};
            acc = __builtin_amdgcn_mfma_f32_16x16x32_bf16(qf[t], kf, acc, 0, 0, 0);
            #pragma unroll
            for (int j = 0; j < 4; ++j) rp += exp2f(acc[j]) * ci[t][j];
        }
        // sum over the 4 lhi groups; n = nt*16 + l15
        rp += __shfl_xor(rp, 16);
        rp += __shfl_xor(rp, 32);
        if (lane < 16) sp[nt * 16 + l15] = rp;
    }
}

// ---------------- Kernel E: reduce s partials over the 16 m-chunks --------------
__global__ __launch_bounds__(256) void reduce_s_kernel(
    const float* __restrict__ spart, float* __restrict__ sfull)
{
    int i = blockIdx.x * 256 + threadIdx.x;   // < BH*N = 65536
    int bh = i >> 10, n = i & (N - 1);
    float acc = 0.f;
    #pragma unroll
    for (int mc = 0; mc < 16; ++mc)
        acc += spart[(size_t)(bh * 16 + mc) * N + n];
    sfull[i] = acc;
}

// ---------------- Kernel F: output GEMM, V-scale fused in-register --------------
// out[m,n] = sum_k (V[m,k] * s[b, k>>5, m&1023]) * Wo[k,n] + bo[n]
__global__ __launch_bounds__(256) void out_mfma(
    const short* __restrict__ Vb16, const float* __restrict__ sfull,
    const short* __restrict__ Wt4,
    const float* __restrict__ bo, float* __restrict__ out)
{
    const short* Wot = Wt4 + (size_t)3 * E * E;
    const int wave = threadIdx.x >> 6, lane = threadIdx.x & 63;
    const int l15 = lane & 15, lhi = lane >> 4;
    const int m0 = blockIdx.x * 64 + wave * 16;
    const int n0 = blockIdx.y * 64;

    // per-lane A-row scale, one per head
    const int r = m0 + l15;
    const int b = r >> 10, nl = r & (N - 1);
    float sarr[8];
    #pragma unroll
    for (int h = 0; h < 8; ++h)
        sarr[h] = sfull[(size_t)(b * H + h) * N + nl];

    const short* vrow = Vb16 + (size_t)r * E + lhi * 8;

    f32x4 acc[4] = {};
    for (int k0 = 0; k0 < E; k0 += 32) {
        const float s = sarr[k0 >> 5];
        short8 vv = *(const short8*)(vrow + k0);
        short at[8];
        #pragma unroll
        for (int i = 0; i < 8; ++i) at[i] = bf16bits(bf16tof(vv[i]) * s);
        short8 af = *(short8*)at;
        #pragma unroll
        for (int nt = 0; nt < 4; ++nt) {
            short8 bf = *(const short8*)(Wot + (size_t)(n0 + nt * 16 + l15) * E + k0 + lhi * 8);
            acc[nt] = __builtin_amdgcn_mfma_f32_16x16x32_bf16(af, bf, acc[nt], 0, 0, 0);
        }
    }
    #pragma unroll
    for (int nt = 0; nt < 4; ++nt) {
        #pragma unroll
        for (int j = 0; j < 4; ++j) {
            int m = m0 + lhi * 4 + j;
            int n = n0 + nt * 16 + l15;
            out[(size_t)m * E + n] = acc[nt][j] + bo[n];
        }
    }
}

// --------------------------------------------------------------------------------
extern "C" void kernel_launch(void* const* d_in, const int* in_sizes, int n_in,
                              void* d_out, int out_size, void* d_ws, size_t ws_size,
                              hipStream_t stream) {
    const float* q_in = (const float*)d_in[0];
    const float* k_in = (const float*)d_in[1];
    const float* v_in = (const float*)d_in[2];
    const float* Wq = (const float*)d_in[3];
    const float* bq = (const float*)d_in[4];
    const float* Wk = (const float*)d_in[5];
    const float* bk = (const float*)d_in[6];
    const float* Wv = (const float*)d_in[7];
    const float* bv = (const float*)d_in[8];
    const float* Wo = (const float*)d_in[9];
    const float* bo = (const float*)d_in[10];
    float* out = (float*)d_out;

    // Workspace layout (bytes):
    //   Wt4   bf16 [4][E][E]    @ 0        (512 KB)
    //   Qb16  bf16 [BH][N][D]   @ 0.5 MB   (4 MB)
    //   Kb16  bf16 [BH][N][D]   @ 4.5 MB   (4 MB)
    //   Vb16  bf16 [R][E]       @ 8.5 MB   (4 MB)
    //   spart fp32 [BH*16][N]   @ 12.5 MB  (4 MB)
    //   sfull fp32 [BH][N]      @ 16.5 MB  (256 KB)  -> total 16.75 MB
    char* ws = (char*)d_ws;
    short*          Wt4   = (short*)ws;
    __hip_bfloat16* Qb16  = (__hip_bfloat16*)(ws + (512u << 10));
    __hip_bfloat16* Kb16  = (__hip_bfloat16*)(ws + (4u << 20) + (512u << 10));
    short*          Vb16  = (short*)(ws + (8u << 20) + (512u << 10));
    float*          spart = (float*)(ws + (12u << 20) + (512u << 10));
    float*          sfull = (float*)(ws + (16u << 20) + (512u << 10));

    convw_kernel<<<dim3(16, 4), 256, 0, stream>>>(Wq, Wk, Wv, Wo, Wt4);

    proj_mfma<<<dim3(R / 64, E / 64, 3), 256, 0, stream>>>(
        q_in, k_in, v_in, Wt4, bq, bk, bv, Qb16, Kb16, Vb16);

    scores_kernel<<<dim3(BH, 16), 256, 0, stream>>>(Qb16, Kb16, spart);

    reduce_s_kernel<<<BH * N / 256, 256, 0, stream>>>(spart, sfull);

    out_mfma<<<dim3(R / 64, E / 64), 256, 0, stream>>>(Vb16, sfull, Wt4, bo, out);
}

// Round 5
// 96.723 us; speedup vs baseline: 1.0366x; 1.0366x over previous
//
#include <hip/hip_runtime.h>
#include <hip/hip_bf16.h>
#include <cstdint>
#include <cstddef>

// Problem constants (B=8, T=64, F=16, E=256, H=8)
constexpr int E = 256;
constexpr int H = 8;
constexpr int D = 32;        // head dim
constexpr int N = 1024;      // T*F positions per (b,h)
constexpr int R = 8192;      // B*N rows
constexpr int BH = 64;       // B*H
constexpr float SCALE = 0.17677669529663687f;   // 1/sqrt(32)
constexpr float LOG2E = 1.4426950408889634f;
constexpr float QSCALE = SCALE * LOG2E;          // folded into bf16 Q

typedef __attribute__((ext_vector_type(8))) short short8;
typedef __attribute__((ext_vector_type(4))) float f32x4;

static __device__ __forceinline__ short bf16bits(float x) {
    __hip_bfloat16 h = __float2bfloat16(x);
    return *reinterpret_cast<short*>(&h);
}
static __device__ __forceinline__ float bf16tof(short s) {
    unsigned int u = ((unsigned int)(unsigned short)s) << 16;
    return *reinterpret_cast<float*>(&u);
}

// ---------------- Kernel B: transpose weights fp32 -> bf16 ---------------------
// Wt4[w][n][k] = W_w[k][n],  w in {q,k,v,o}
__global__ __launch_bounds__(256) void convw_kernel(
    const float* __restrict__ Wq, const float* __restrict__ Wk,
    const float* __restrict__ Wv, const float* __restrict__ Wo,
    short* __restrict__ Wt4)
{
    const int w = blockIdx.y;
    const float* src = (w == 0) ? Wq : (w == 1) ? Wk : (w == 2) ? Wv : Wo;
    short* dst = Wt4 + (size_t)w * E * E;
    const int tr = blockIdx.x >> 2, tc = blockIdx.x & 3;   // 64x64 tiles
    __shared__ float tile[64][65];
    const int tid = threadIdx.x;
    #pragma unroll
    for (int it = 0; it < 16; ++it) {
        int idx = tid + it * 256;
        int r = idx >> 6, c = idx & 63;
        tile[r][c] = src[(size_t)(tr * 64 + r) * E + tc * 64 + c];
    }
    __syncthreads();
    #pragma unroll
    for (int it = 0; it < 16; ++it) {
        int idx = tid + it * 256;
        int r = idx >> 6, c = idx & 63;
        dst[(size_t)(tc * 64 + r) * E + tr * 64 + c] = bf16bits(tile[c][r]);
    }
}

// ---------------- Kernel C: fused QKV projections via MFMA ---------------------
// Block: 64 m x 128 n, 4 waves (wave = 16 m x 128 n, acc 8 x f32x4).
// Q -> bf16 head-split *QSCALE; K -> bf16 head-split; V -> bf16 row-major.
__global__ __launch_bounds__(256) void proj_mfma(
    const float* __restrict__ q_in, const float* __restrict__ k_in, const float* __restrict__ v_in,
    const short* __restrict__ Wt4,
    const float* __restrict__ bq, const float* __restrict__ bk, const float* __restrict__ bv,
    __hip_bfloat16* __restrict__ Qb16, __hip_bfloat16* __restrict__ Kb16,
    short* __restrict__ Vb16)
{
    const int which = blockIdx.z;
    const float* X  = (which == 0) ? q_in : (which == 1) ? k_in : v_in;
    const short* Wt = Wt4 + (size_t)which * E * E;
    const float* bias = (which == 0) ? bq : (which == 1) ? bk : bv;

    const int wave = threadIdx.x >> 6, lane = threadIdx.x & 63;
    const int l15 = lane & 15, lhi = lane >> 4;
    const int m0 = blockIdx.x * 64 + wave * 16;
    const int n0 = blockIdx.y * 128;

    const float* xrow = X + (size_t)(m0 + l15) * E + lhi * 8;

    f32x4 acc[8] = {};
    for (int k0 = 0; k0 < E; k0 += 32) {
        float4 a0 = *(const float4*)(xrow + k0);
        float4 a1 = *(const float4*)(xrow + k0 + 4);
        short at[8];
        at[0] = bf16bits(a0.x); at[1] = bf16bits(a0.y);
        at[2] = bf16bits(a0.z); at[3] = bf16bits(a0.w);
        at[4] = bf16bits(a1.x); at[5] = bf16bits(a1.y);
        at[6] = bf16bits(a1.z); at[7] = bf16bits(a1.w);
        short8 af = *(short8*)at;
        #pragma unroll
        for (int nt = 0; nt < 8; ++nt) {
            short8 bf = *(const short8*)(Wt + (size_t)(n0 + nt * 16 + l15) * E + k0 + lhi * 8);
            acc[nt] = __builtin_amdgcn_mfma_f32_16x16x32_bf16(af, bf, acc[nt], 0, 0, 0);
        }
    }
    // D layout: row m = m0 + lhi*4 + j (A rows), col n = n0 + nt*16 + l15 (B rows)
    #pragma unroll
    for (int nt = 0; nt < 8; ++nt) {
        #pragma unroll
        for (int j = 0; j < 4; ++j) {
            int m = m0 + lhi * 4 + j;
            int n = n0 + nt * 16 + l15;
            float v = acc[nt][j] + bias[n];
            if (which == 2) {
                Vb16[(size_t)m * E + n] = bf16bits(v);
            } else {
                int b = m >> 10, nl = m & (N - 1);
                int h = n >> 5, dd = n & 31;
                size_t idx = ((size_t)((b * H + h) * N + nl)) * D + dd;
                if (which == 0) Qb16[idx] = __float2bfloat16(v * QSCALE);
                else            Kb16[idx] = __float2bfloat16(v);
            }
        }
    }
}

// ---------------- Kernel D1: Z partials --------------------------------------
// Grid (BH, 16 mc, 2 nc) = 2048 blocks, 4 waves. Wave: 4 m-tiles x 8 n-tiles.
// zpart[bh][nc][m] = sum_{n in nc half} exp2(S[n,m])
__global__ __launch_bounds__(256) void zpart_kernel(
    const __hip_bfloat16* __restrict__ Qb16, const __hip_bfloat16* __restrict__ Kb16,
    float* __restrict__ zpart)
{
    const int bh = blockIdx.x;   // 0..63
    const int mc = blockIdx.y;   // 0..15
    const int nc = blockIdx.z;   // 0..1
    const int tid  = threadIdx.x;
    const int wave = tid >> 6;
    const int lane = tid & 63;
    const int l15  = lane & 15;
    const int lhi  = lane >> 4;

    const short* Qb = (const short*)Qb16 + (size_t)bh * (N * D);
    const short* Kb = (const short*)Kb16 + (size_t)bh * (N * D);

    __shared__ float zred[4][64];

    short8 qf[4];
    #pragma unroll
    for (int t = 0; t < 4; ++t) {
        int m = mc * 64 + t * 16 + l15;
        qf[t] = *(const short8*)(Qb + (size_t)m * D + lhi * 8);
    }

    float z[4][4];
    #pragma unroll
    for (int t = 0; t < 4; ++t)
        #pragma unroll
        for (int j = 0; j < 4; ++j) z[t][j] = 0.f;

    #pragma unroll 2
    for (int ntl = 0; ntl < 8; ++ntl) {
        int nt = nc * 32 + wave * 8 + ntl;
        short8 kf = *(const short8*)(Kb + (size_t)(nt * 16 + l15) * D + lhi * 8);
        #pragma unroll
        for (int t = 0; t < 4; ++t) {
            f32x4 acc = {0.f, 0.f, 0.f, 0.f};
            acc = __builtin_amdgcn_mfma_f32_16x16x32_bf16(qf[t], kf, acc, 0, 0, 0);
            #pragma unroll
            for (int j = 0; j < 4; ++j) z[t][j] += exp2f(acc[j]);
        }
    }
    // butterfly over l15 (sums the 16 n's per tile)
    #pragma unroll
    for (int t = 0; t < 4; ++t)
        #pragma unroll
        for (int j = 0; j < 4; ++j) {
            float v = z[t][j];
            v += __shfl_xor(v, 1); v += __shfl_xor(v, 2);
            v += __shfl_xor(v, 4); v += __shfl_xor(v, 8);
            z[t][j] = v;
        }
    #pragma unroll
    for (int t = 0; t < 4; ++t) {
        if (l15 == t) {
            #pragma unroll
            for (int j = 0; j < 4; ++j)
                zred[wave][t * 16 + lhi * 4 + j] = z[t][j];
        }
    }
    __syncthreads();
    if (tid < 64) {
        float zs = zred[0][tid] + zred[1][tid] + zred[2][tid] + zred[3][tid];
        zpart[((size_t)(bh * 2 + nc)) * N + mc * 64 + tid] = zs;
    }
}

// ---------------- Kernel D2: weighted row-sum partials ------------------------
// Grid (BH, 16 mc, 2 nc). Computes cinv from zpart halves, then
// spart[bh][mc][n] = sum_{m in mc} exp2(S[n,m]) / Z_m  for n in nc half.
__global__ __launch_bounds__(256) void spart_kernel(
    const __hip_bfloat16* __restrict__ Qb16, const __hip_bfloat16* __restrict__ Kb16,
    const float* __restrict__ zpart, float* __restrict__ spart)
{
    const int bh = blockIdx.x;
    const int mc = blockIdx.y;
    const int nc = blockIdx.z;
    const int tid  = threadIdx.x;
    const int wave = tid >> 6;
    const int lane = tid & 63;
    const int l15  = lane & 15;
    const int lhi  = lane >> 4;

    const short* Qb = (const short*)Qb16 + (size_t)bh * (N * D);
    const short* Kb = (const short*)Kb16 + (size_t)bh * (N * D);

    __shared__ float cinvS[64];
    if (tid < 64) {
        int m = mc * 64 + tid;
        float zs = zpart[((size_t)(bh * 2 + 0)) * N + m] +
                   zpart[((size_t)(bh * 2 + 1)) * N + m];
        cinvS[tid] = 1.0f / zs;
    }

    short8 qf[4];
    #pragma unroll
    for (int t = 0; t < 4; ++t) {
        int m = mc * 64 + t * 16 + l15;
        qf[t] = *(const short8*)(Qb + (size_t)m * D + lhi * 8);
    }
    __syncthreads();

    float ci[4][4];
    #pragma unroll
    for (int t = 0; t < 4; ++t)
        #pragma unroll
        for (int j = 0; j < 4; ++j) ci[t][j] = cinvS[t * 16 + lhi * 4 + j];

    float* sp = spart + (size_t)(bh * 16 + mc) * N;
    #pragma unroll 2
    for (int ntl = 0; ntl < 8; ++ntl) {
        int nt = nc * 32 + wave * 8 + ntl;
        short8 kf = *(const short8*)(Kb + (size_t)(nt * 16 + l15) * D + lhi * 8);
        float rp = 0.f;
        #pragma unroll
        for (int t = 0; t < 4; ++t) {
            f32x4 acc = {0.f, 0.f, 0.f, 0.f};
            acc = __builtin_amdgcn_mfma_f32_16x16x32_bf16(qf[t], kf, acc, 0, 0, 0);
            #pragma unroll
            for (int j = 0; j < 4; ++j) rp += exp2f(acc[j]) * ci[t][j];
        }
        // sum over the 4 lhi groups; n = nt*16 + l15
        rp += __shfl_xor(rp, 16);
        rp += __shfl_xor(rp, 32);
        if (lane < 16) sp[nt * 16 + l15] = rp;
    }
}

// ---------------- Kernel F: output GEMM, s-reduce + V-scale fused --------------
// Block: 64 m x 128 n. LDS table sfl[h][r_loc] = sum_mc spart (the per-row,
// per-head total attention weight), then A-frag = bf16(V * s) in-register.
__global__ __launch_bounds__(256) void out_mfma(
    const short* __restrict__ Vb16, const float* __restrict__ spart,
    const short* __restrict__ Wt4,
    const float* __restrict__ bo, float* __restrict__ out)
{
    const short* Wot = Wt4 + (size_t)3 * E * E;
    const int wave = threadIdx.x >> 6, lane = threadIdx.x & 63;
    const int l15 = lane & 15, lhi = lane >> 4;
    const int m0 = blockIdx.x * 64;
    const int n0 = blockIdx.y * 128;
    const int b  = m0 >> 10;
    const int nl0 = m0 & (N - 1);

    __shared__ float sfl[8][64];
    {
        int r_loc = threadIdx.x & 63;
        int h0 = threadIdx.x >> 6;   // 0..3
        #pragma unroll
        for (int hh = 0; hh < 2; ++hh) {
            int h = h0 + hh * 4;
            const float* spp = spart + ((size_t)((b * H + h) * 16)) * N + nl0 + r_loc;
            float s = 0.f;
            #pragma unroll
            for (int mc = 0; mc < 16; ++mc) s += spp[(size_t)mc * N];
            sfl[h][r_loc] = s;
        }
    }
    __syncthreads();

    const int r = m0 + wave * 16 + l15;
    float sarr[8];
    #pragma unroll
    for (int h = 0; h < 8; ++h) sarr[h] = sfl[h][wave * 16 + l15];

    const short* vrow = Vb16 + (size_t)r * E + lhi * 8;

    f32x4 acc[8] = {};
    for (int k0 = 0; k0 < E; k0 += 32) {
        const float s = sarr[k0 >> 5];
        short8 vv = *(const short8*)(vrow + k0);
        short at[8];
        #pragma unroll
        for (int i = 0; i < 8; ++i) at[i] = bf16bits(bf16tof(vv[i]) * s);
        short8 af = *(short8*)at;
        #pragma unroll
        for (int nt = 0; nt < 8; ++nt) {
            short8 bf = *(const short8*)(Wot + (size_t)(n0 + nt * 16 + l15) * E + k0 + lhi * 8);
            acc[nt] = __builtin_amdgcn_mfma_f32_16x16x32_bf16(af, bf, acc[nt], 0, 0, 0);
        }
    }
    #pragma unroll
    for (int nt = 0; nt < 8; ++nt) {
        #pragma unroll
        for (int j = 0; j < 4; ++j) {
            int m = m0 + wave * 16 + lhi * 4 + j;
            int n = n0 + nt * 16 + l15;
            out[(size_t)m * E + n] = acc[nt][j] + bo[n];
        }
    }
}

// --------------------------------------------------------------------------------
extern "C" void kernel_launch(void* const* d_in, const int* in_sizes, int n_in,
                              void* d_out, int out_size, void* d_ws, size_t ws_size,
                              hipStream_t stream) {
    const float* q_in = (const float*)d_in[0];
    const float* k_in = (const float*)d_in[1];
    const float* v_in = (const float*)d_in[2];
    const float* Wq = (const float*)d_in[3];
    const float* bq = (const float*)d_in[4];
    const float* Wk = (const float*)d_in[5];
    const float* bk = (const float*)d_in[6];
    const float* Wv = (const float*)d_in[7];
    const float* bv = (const float*)d_in[8];
    const float* Wo = (const float*)d_in[9];
    const float* bo = (const float*)d_in[10];
    float* out = (float*)d_out;

    // Workspace layout (bytes):
    //   Wt4   bf16 [4][E][E]     @ 0        (512 KB)
    //   Qb16  bf16 [BH][N][D]    @ 0.5 MB   (4 MB)
    //   Kb16  bf16 [BH][N][D]    @ 4.5 MB   (4 MB)
    //   Vb16  bf16 [R][E]        @ 8.5 MB   (4 MB)
    //   zpart fp32 [BH][2][N]    @ 12.5 MB  (512 KB)
    //   spart fp32 [BH*16][N]    @ 13 MB    (4 MB)   -> total 17 MB
    char* ws = (char*)d_ws;
    short*          Wt4   = (short*)ws;
    __hip_bfloat16* Qb16  = (__hip_bfloat16*)(ws + (512u << 10));
    __hip_bfloat16* Kb16  = (__hip_bfloat16*)(ws + (4u << 20) + (512u << 10));
    short*          Vb16  = (short*)(ws + (8u << 20) + (512u << 10));
    float*          zpart = (float*)(ws + (12u << 20) + (512u << 10));
    float*          spart = (float*)(ws + (13u << 20));

    convw_kernel<<<dim3(16, 4), 256, 0, stream>>>(Wq, Wk, Wv, Wo, Wt4);

    proj_mfma<<<dim3(R / 64, 2, 3), 256, 0, stream>>>(
        q_in, k_in, v_in, Wt4, bq, bk, bv, Qb16, Kb16, Vb16);

    zpart_kernel<<<dim3(BH, 16, 2), 256, 0, stream>>>(Qb16, Kb16, zpart);

    spart_kernel<<<dim3(BH, 16, 2), 256, 0, stream>>>(Qb16, Kb16, zpart, spart);

    out_mfma<<<dim3(R / 64, 2), 256, 0, stream>>>(Vb16, spart, Wt4, bo, out);
}

// Round 6
// 80.815 us; speedup vs baseline: 1.2407x; 1.1968x over previous
//
#include <hip/hip_runtime.h>
#include <hip/hip_bf16.h>
#include <cstdint>
#include <cstddef>

// Problem constants (B=8, T=64, F=16, E=256, H=8)
constexpr int E = 256;
constexpr int H = 8;
constexpr int D = 32;        // head dim
constexpr int N = 1024;      // T*F positions per (b,h)
constexpr int R = 8192;      // B*N rows
constexpr int BH = 64;       // B*H
constexpr float SCALE = 0.17677669529663687f;   // 1/sqrt(32)
constexpr float LOG2E = 1.4426950408889634f;
constexpr float QSCALE = SCALE * LOG2E;          // folded into bf16 Q

typedef __attribute__((ext_vector_type(8))) short short8;
typedef __attribute__((ext_vector_type(4))) short short4v;
typedef __attribute__((ext_vector_type(4))) float f32x4;

static __device__ __forceinline__ short bf16bits(float x) {
    __hip_bfloat16 h = __float2bfloat16(x);
    return *reinterpret_cast<short*>(&h);
}
static __device__ __forceinline__ float bf16tof(short s) {
    unsigned int u = ((unsigned int)(unsigned short)s) << 16;
    return *reinterpret_cast<float*>(&u);
}

// ---------------- Kernel B: transpose weights fp32 -> bf16 ---------------------
// Wt4[w][n][k] = W_w[k][n],  w in {q,k,v,o}
__global__ __launch_bounds__(256) void convw_kernel(
    const float* __restrict__ Wq, const float* __restrict__ Wk,
    const float* __restrict__ Wv, const float* __restrict__ Wo,
    short* __restrict__ Wt4)
{
    const int w = blockIdx.y;
    const float* src = (w == 0) ? Wq : (w == 1) ? Wk : (w == 2) ? Wv : Wo;
    short* dst = Wt4 + (size_t)w * E * E;
    const int tr = blockIdx.x >> 2, tc = blockIdx.x & 3;   // 64x64 tiles
    __shared__ float tile[64][65];
    const int tid = threadIdx.x;
    #pragma unroll
    for (int it = 0; it < 16; ++it) {
        int idx = tid + it * 256;
        int r = idx >> 6, c = idx & 63;
        tile[r][c] = src[(size_t)(tr * 64 + r) * E + tc * 64 + c];
    }
    __syncthreads();
    #pragma unroll
    for (int it = 0; it < 16; ++it) {
        int idx = tid + it * 256;
        int r = idx >> 6, c = idx & 63;
        dst[(size_t)(tc * 64 + r) * E + tr * 64 + c] = bf16bits(tile[c][r]);
    }
}

// ---------------- Kernel C: fused QKV projections via MFMA ---------------------
// Block: 64 m x 128 n, 4 waves (wave = 16 m x 128 n, acc 8 x f32x4).
// Q -> bf16 head-split *QSCALE; K -> bf16 head-split; V -> bf16 row-major.
__global__ __launch_bounds__(256) void proj_mfma(
    const float* __restrict__ q_in, const float* __restrict__ k_in, const float* __restrict__ v_in,
    const short* __restrict__ Wt4,
    const float* __restrict__ bq, const float* __restrict__ bk, const float* __restrict__ bv,
    __hip_bfloat16* __restrict__ Qb16, __hip_bfloat16* __restrict__ Kb16,
    short* __restrict__ Vb16)
{
    const int which = blockIdx.z;
    const float* X  = (which == 0) ? q_in : (which == 1) ? k_in : v_in;
    const short* Wt = Wt4 + (size_t)which * E * E;
    const float* bias = (which == 0) ? bq : (which == 1) ? bk : bv;

    const int wave = threadIdx.x >> 6, lane = threadIdx.x & 63;
    const int l15 = lane & 15, lhi = lane >> 4;
    const int m0 = blockIdx.x * 64 + wave * 16;
    const int n0 = blockIdx.y * 128;

    const float* xrow = X + (size_t)(m0 + l15) * E + lhi * 8;

    f32x4 acc[8] = {};
    for (int k0 = 0; k0 < E; k0 += 32) {
        float4 a0 = *(const float4*)(xrow + k0);
        float4 a1 = *(const float4*)(xrow + k0 + 4);
        short at[8];
        at[0] = bf16bits(a0.x); at[1] = bf16bits(a0.y);
        at[2] = bf16bits(a0.z); at[3] = bf16bits(a0.w);
        at[4] = bf16bits(a1.x); at[5] = bf16bits(a1.y);
        at[6] = bf16bits(a1.z); at[7] = bf16bits(a1.w);
        short8 af = *(short8*)at;
        #pragma unroll
        for (int nt = 0; nt < 8; ++nt) {
            short8 bf = *(const short8*)(Wt + (size_t)(n0 + nt * 16 + l15) * E + k0 + lhi * 8);
            acc[nt] = __builtin_amdgcn_mfma_f32_16x16x32_bf16(af, bf, acc[nt], 0, 0, 0);
        }
    }
    // D layout: row m = m0 + lhi*4 + j (A rows), col n = n0 + nt*16 + l15 (B rows)
    #pragma unroll
    for (int nt = 0; nt < 8; ++nt) {
        #pragma unroll
        for (int j = 0; j < 4; ++j) {
            int m = m0 + lhi * 4 + j;
            int n = n0 + nt * 16 + l15;
            float v = acc[nt][j] + bias[n];
            if (which == 2) {
                Vb16[(size_t)m * E + n] = bf16bits(v);
            } else {
                int b = m >> 10, nl = m & (N - 1);
                int h = n >> 5, dd = n & 31;
                size_t idx = ((size_t)((b * H + h) * N + nl)) * D + dd;
                if (which == 0) Qb16[idx] = __float2bfloat16(v * QSCALE);
                else            Kb16[idx] = __float2bfloat16(v);
            }
        }
    }
}

// ---------------- Kernel D: fused scores softmax (single QK^T pass) ------------
// Grid (BH, 32 mc) x 512 threads (8 waves). Block: 32 m columns, ALL 1024 n.
// Wave w: n-tiles w*8..w*8+7 (128 rows), m-tiles t=0,1.
// Pass A: acc = mfma(qf[t], kf) -> lane holds 8 m x 1 n per (t,ntl);
//         e = exp2(acc) accumulated into z AND parked as packed bf16 in VGPRs.
// Block-reduce z -> cinv[32] (1 KB LDS).
// Pass B: pure-register rp = sum_{t,j} e * cinv, 2 shuffles, store s partial.
__global__ __launch_bounds__(512, 4) void scores_fused(
    const __hip_bfloat16* __restrict__ Qb16, const __hip_bfloat16* __restrict__ Kb16,
    float* __restrict__ spart)
{
    const int bh = blockIdx.x;   // 0..63
    const int mc = blockIdx.y;   // 0..31
    const int tid  = threadIdx.x;
    const int wave = tid >> 6;   // 0..7
    const int lane = tid & 63;
    const int l15  = lane & 15;
    const int lhi  = lane >> 4;

    const short* Qb = (const short*)Qb16 + (size_t)bh * (N * D);
    const short* Kb = (const short*)Kb16 + (size_t)bh * (N * D);

    __shared__ float zred[8][32];
    __shared__ float cinvS[32];

    short8 qf[2];
    #pragma unroll
    for (int t = 0; t < 2; ++t) {
        int m = mc * 32 + t * 16 + l15;
        qf[t] = *(const short8*)(Qb + (size_t)m * D + lhi * 8);
    }

    float z[2][4];
    #pragma unroll
    for (int t = 0; t < 2; ++t)
        #pragma unroll
        for (int j = 0; j < 4; ++j) z[t][j] = 0.f;

    short4v ep[2][8];   // parked P = exp2(S), packed bf16 (32 VGPRs)

    // ---- Pass A ----
    #pragma unroll
    for (int ntl = 0; ntl < 8; ++ntl) {
        int nt = wave * 8 + ntl;
        short8 kf = *(const short8*)(Kb + (size_t)(nt * 16 + l15) * D + lhi * 8);
        #pragma unroll
        for (int t = 0; t < 2; ++t) {
            f32x4 acc = {0.f, 0.f, 0.f, 0.f};
            acc = __builtin_amdgcn_mfma_f32_16x16x32_bf16(qf[t], kf, acc, 0, 0, 0);
            float e0 = exp2f(acc[0]), e1 = exp2f(acc[1]);
            float e2 = exp2f(acc[2]), e3 = exp2f(acc[3]);
            z[t][0] += e0; z[t][1] += e1; z[t][2] += e2; z[t][3] += e3;
            short4v pk = { bf16bits(e0), bf16bits(e1), bf16bits(e2), bf16bits(e3) };
            ep[t][ntl] = pk;
        }
    }

    // butterfly over l15 (sums the 16 n's per tile; ntl already accumulated)
    #pragma unroll
    for (int t = 0; t < 2; ++t)
        #pragma unroll
        for (int j = 0; j < 4; ++j) {
            float v = z[t][j];
            v += __shfl_xor(v, 1); v += __shfl_xor(v, 2);
            v += __shfl_xor(v, 4); v += __shfl_xor(v, 8);
            z[t][j] = v;
        }
    // z[t][j] = partial Z (this wave's 128 n) for m_local = t*16 + lhi*4 + j
    #pragma unroll
    for (int t = 0; t < 2; ++t) {
        if (l15 == t) {
            #pragma unroll
            for (int j = 0; j < 4; ++j)
                zred[wave][t * 16 + lhi * 4 + j] = z[t][j];
        }
    }
    __syncthreads();
    if (tid < 32) {
        float zs = 0.f;
        #pragma unroll
        for (int w = 0; w < 8; ++w) zs += zred[w][tid];
        cinvS[tid] = 1.0f / zs;
    }
    __syncthreads();

    float ci[2][4];
    #pragma unroll
    for (int t = 0; t < 2; ++t)
        #pragma unroll
        for (int j = 0; j < 4; ++j) ci[t][j] = cinvS[t * 16 + lhi * 4 + j];

    // ---- Pass B: pure-register weighted row sums ----
    float* sp = spart + (size_t)(bh * 32 + mc) * N;
    #pragma unroll
    for (int ntl = 0; ntl < 8; ++ntl) {
        int nt = wave * 8 + ntl;
        float rp = 0.f;
        #pragma unroll
        for (int t = 0; t < 2; ++t)
            #pragma unroll
            for (int j = 0; j < 4; ++j)
                rp += bf16tof(ep[t][ntl][j]) * ci[t][j];
        // sum over the 4 lhi groups (m sub-ranges); n = nt*16 + l15
        rp += __shfl_xor(rp, 16);
        rp += __shfl_xor(rp, 32);
        if (lane < 16) sp[nt * 16 + l15] = rp;
    }
}

// ---------------- Kernel F: output GEMM, s-reduce + V-scale fused --------------
// Block: 64 m x 64 n, 4 waves. LDS prologue: sfl[h][r_loc] = sum_mc spart
// (per-row, per-head total attention weight); A-frag = bf16(V * s) in-register.
__global__ __launch_bounds__(256) void out_mfma(
    const short* __restrict__ Vb16, const float* __restrict__ spart,
    const short* __restrict__ Wt4,
    const float* __restrict__ bo, float* __restrict__ out)
{
    const short* Wot = Wt4 + (size_t)3 * E * E;
    const int wave = threadIdx.x >> 6, lane = threadIdx.x & 63;
    const int l15 = lane & 15, lhi = lane >> 4;
    const int m0 = blockIdx.x * 64;
    const int n0 = blockIdx.y * 64;
    const int b  = m0 >> 10;
    const int nl0 = m0 & (N - 1);

    __shared__ float sfl[8][64];
    {
        int r_loc = threadIdx.x & 63;
        int h0 = threadIdx.x >> 6;   // 0..3
        #pragma unroll
        for (int hh = 0; hh < 2; ++hh) {
            int h = h0 + hh * 4;
            const float* spp = spart + ((size_t)((b * H + h) * 32)) * N + nl0 + r_loc;
            float s = 0.f;
            #pragma unroll
            for (int mc = 0; mc < 32; ++mc) s += spp[(size_t)mc * N];
            sfl[h][r_loc] = s;
        }
    }
    __syncthreads();

    const int r = m0 + wave * 16 + l15;
    float sarr[8];
    #pragma unroll
    for (int h = 0; h < 8; ++h) sarr[h] = sfl[h][wave * 16 + l15];

    const short* vrow = Vb16 + (size_t)r * E + lhi * 8;

    f32x4 acc[4] = {};
    for (int k0 = 0; k0 < E; k0 += 32) {
        const float s = sarr[k0 >> 5];
        short8 vv = *(const short8*)(vrow + k0);
        short at[8];
        #pragma unroll
        for (int i = 0; i < 8; ++i) at[i] = bf16bits(bf16tof(vv[i]) * s);
        short8 af = *(short8*)at;
        #pragma unroll
        for (int nt = 0; nt < 4; ++nt) {
            short8 bf = *(const short8*)(Wot + (size_t)(n0 + nt * 16 + l15) * E + k0 + lhi * 8);
            acc[nt] = __builtin_amdgcn_mfma_f32_16x16x32_bf16(af, bf, acc[nt], 0, 0, 0);
        }
    }
    #pragma unroll
    for (int nt = 0; nt < 4; ++nt) {
        #pragma unroll
        for (int j = 0; j < 4; ++j) {
            int m = m0 + wave * 16 + lhi * 4 + j;
            int n = n0 + nt * 16 + l15;
            out[(size_t)m * E + n] = acc[nt][j] + bo[n];
        }
    }
}

// --------------------------------------------------------------------------------
extern "C" void kernel_launch(void* const* d_in, const int* in_sizes, int n_in,
                              void* d_out, int out_size, void* d_ws, size_t ws_size,
                              hipStream_t stream) {
    const float* q_in = (const float*)d_in[0];
    const float* k_in = (const float*)d_in[1];
    const float* v_in = (const float*)d_in[2];
    const float* Wq = (const float*)d_in[3];
    const float* bq = (const float*)d_in[4];
    const float* Wk = (const float*)d_in[5];
    const float* bk = (const float*)d_in[6];
    const float* Wv = (const float*)d_in[7];
    const float* bv = (const float*)d_in[8];
    const float* Wo = (const float*)d_in[9];
    const float* bo = (const float*)d_in[10];
    float* out = (float*)d_out;

    // Workspace layout (bytes):
    //   Wt4   bf16 [4][E][E]     @ 0        (512 KB)
    //   Qb16  bf16 [BH][N][D]    @ 0.5 MB   (4 MB)
    //   Kb16  bf16 [BH][N][D]    @ 4.5 MB   (4 MB)
    //   Vb16  bf16 [R][E]        @ 8.5 MB   (4 MB)
    //   spart fp32 [BH*32][N]    @ 12.5 MB  (8 MB)   -> total 20.5 MB
    char* ws = (char*)d_ws;
    short*          Wt4   = (short*)ws;
    __hip_bfloat16* Qb16  = (__hip_bfloat16*)(ws + (512u << 10));
    __hip_bfloat16* Kb16  = (__hip_bfloat16*)(ws + (4u << 20) + (512u << 10));
    short*          Vb16  = (short*)(ws + (8u << 20) + (512u << 10));
    float*          spart = (float*)(ws + (12u << 20) + (512u << 10));

    convw_kernel<<<dim3(16, 4), 256, 0, stream>>>(Wq, Wk, Wv, Wo, Wt4);

    proj_mfma<<<dim3(R / 64, 2, 3), 256, 0, stream>>>(
        q_in, k_in, v_in, Wt4, bq, bk, bv, Qb16, Kb16, Vb16);

    scores_fused<<<dim3(BH, 32), 512, 0, stream>>>(Qb16, Kb16, spart);

    out_mfma<<<dim3(R / 64, E / 64), 256, 0, stream>>>(Vb16, spart, Wt4, bo, out);
}